// Round 3
// baseline (590.357 us; speedup 1.0000x reference)
//
#include <hip/hip_runtime.h>
#include <hip/hip_bf16.h>
#include <math.h>

typedef __bf16 bf16;
typedef __bf16 bf16x8 __attribute__((ext_vector_type(8)));
typedef float f32x4 __attribute__((ext_vector_type(4)));

#define BM 128
#define BN 128
#define BK 32

__device__ __forceinline__ void gload_lds16(const bf16* g, bf16* l) {
  __builtin_amdgcn_global_load_lds(
      (const __attribute__((address_space(1))) void*)g,
      (__attribute__((address_space(3))) void*)l, 16, 0, 0);
}

// C[M,N] = A[M,K] @ BT[N,K]^T, bf16 inputs, fp32 accum.
// EPI 0: out bf16 = acc + bias
// EPI 1: out f32  = acc + bias + res
// EPI 2: out bf16 = gelu_exact(acc + bias)
template <int EPI>
__global__ __launch_bounds__(256, 2)
void gemm_bt(const bf16* __restrict__ A, const bf16* __restrict__ BT,
             const float* __restrict__ bias, const float* __restrict__ res,
             void* __restrict__ Cout, int M, int N, int K)
{
  __shared__ alignas(16) bf16 lsA[BM * BK];
  __shared__ alignas(16) bf16 lsB[BN * BK];

  int nbn = N / BN;
  int nwg = (M / BM) * nbn;
  int bid = blockIdx.x;
  int cpx = nwg >> 3;                       // all grids divisible by 8
  int wg  = (bid & 7) * cpx + (bid >> 3);   // XCD-aware swizzle (bijective)
  int m0 = (wg / nbn) * BM;
  int n0 = (wg % nbn) * BN;

  int t  = threadIdx.x;
  int l  = t & 63;
  int w  = t >> 6;
  int wm = (w >> 1) * 64;
  int wn = (w & 1) * 64;
  int lr = l & 15;
  int lg = l >> 4;

  f32x4 acc[4][4];
  f32x4 zero = {0.f, 0.f, 0.f, 0.f};
#pragma unroll
  for (int mi = 0; mi < 4; ++mi)
#pragma unroll
    for (int ni = 0; ni < 4; ++ni) acc[mi][ni] = zero;

  for (int k0 = 0; k0 < K; k0 += BK) {
#pragma unroll
    for (int i = 0; i < 2; ++i) {
      int c = i * 256 + t;
      gload_lds16(A  + (size_t)(m0 + (c >> 2)) * K + k0 + ((c & 3) << 3), &lsA[c * 8]);
      gload_lds16(BT + (size_t)(n0 + (c >> 2)) * K + k0 + ((c & 3) << 3), &lsB[c * 8]);
    }
    __syncthreads();

    bf16x8 af[4], bfr[4];
#pragma unroll
    for (int mi = 0; mi < 4; ++mi)
      af[mi] = *(const bf16x8*)&lsA[(wm + mi * 16 + lr) * BK + lg * 8];
#pragma unroll
    for (int ni = 0; ni < 4; ++ni)
      bfr[ni] = *(const bf16x8*)&lsB[(wn + ni * 16 + lr) * BK + lg * 8];

#pragma unroll
    for (int mi = 0; mi < 4; ++mi)
#pragma unroll
      for (int ni = 0; ni < 4; ++ni)
        acc[mi][ni] = __builtin_amdgcn_mfma_f32_16x16x32_bf16(af[mi], bfr[ni], acc[mi][ni], 0, 0, 0);
    __syncthreads();
  }

#pragma unroll
  for (int mi = 0; mi < 4; ++mi) {
    int row = m0 + wm + mi * 16 + lg * 4;
#pragma unroll
    for (int ni = 0; ni < 4; ++ni) {
      int col = n0 + wn + ni * 16 + lr;
      float bv = bias[col];
      f32x4 a = acc[mi][ni];
#pragma unroll
      for (int r = 0; r < 4; ++r) {
        float v = a[r] + bv;
        size_t idx = (size_t)(row + r) * N + col;
        if (EPI == 0) {
          ((bf16*)Cout)[idx] = (bf16)v;
        } else if (EPI == 1) {
          ((float*)Cout)[idx] = v + res[idx];
        } else {
          v = 0.5f * v * (1.f + erff(v * 0.70710678118654752f));
          ((bf16*)Cout)[idx] = (bf16)v;
        }
      }
    }
  }
}

// LayerNorm over last dim (1024), fp32 in -> bf16 out. One block per row.
__global__ __launch_bounds__(256)
void ln_bf16(const float* __restrict__ x, const float* __restrict__ w,
             const float* __restrict__ b, bf16* __restrict__ out)
{
  int row = blockIdx.x;
  int t = threadIdx.x;
  float4 v = ((const float4*)(x + (size_t)row * 1024))[t];
  float s  = v.x + v.y + v.z + v.w;
  float sq = v.x * v.x + v.y * v.y + v.z * v.z + v.w * v.w;
#pragma unroll
  for (int off = 32; off >= 1; off >>= 1) {
    s  += __shfl_xor(s, off);
    sq += __shfl_xor(sq, off);
  }
  __shared__ float ps[4], pq[4];
  if ((t & 63) == 0) { ps[t >> 6] = s; pq[t >> 6] = sq; }
  __syncthreads();
  s  = ps[0] + ps[1] + ps[2] + ps[3];
  sq = pq[0] + pq[1] + pq[2] + pq[3];
  float mu  = s * (1.f / 1024.f);
  float var = sq * (1.f / 1024.f) - mu * mu;
  float rstd = rsqrtf(var + 1e-5f);
  float4 wv = ((const float4*)w)[t];
  float4 bv = ((const float4*)b)[t];
  size_t o0 = (size_t)row * 1024 + t * 4;
  out[o0 + 0] = (bf16)((v.x - mu) * rstd * wv.x + bv.x);
  out[o0 + 1] = (bf16)((v.y - mu) * rstd * wv.y + bv.y);
  out[o0 + 2] = (bf16)((v.z - mu) * rstd * wv.z + bv.z);
  out[o0 + 3] = (bf16)((v.w - mu) * rstd * wv.w + bv.w);
}

// WT[N,K] (bf16) = W[K,N] (f32) transposed+cast. grid=(K/32, N/32), 256 thr.
__global__ __launch_bounds__(256)
void transpose_cast(const float* __restrict__ W, bf16* __restrict__ WT, int K, int N)
{
  __shared__ float tile[32][33];
  int bk = blockIdx.x * 32, bn = blockIdx.y * 32;
  int tx = threadIdx.x & 31, ty = threadIdx.x >> 5;
#pragma unroll
  for (int i = ty; i < 32; i += 8)
    tile[i][tx] = W[(size_t)(bk + i) * N + bn + tx];
  __syncthreads();
#pragma unroll
  for (int i = ty; i < 32; i += 8)
    WT[(size_t)(bn + i) * K + bk + tx] = (bf16)tile[tx][i];
}

// V transpose: vt[(b*16+h)*64 + d][t] = qkv[(b*2048+t)*3072 + 2048 + h*64 + d]
// 64 tokens x 64 dims per block; XOR-swizzled LDS chunks. grid=(64, 32).
__global__ __launch_bounds__(256)
void vtrans(const bf16* __restrict__ qkv, bf16* __restrict__ vt)
{
  __shared__ alignas(16) bf16 tile[64 * 64];
  int bh = blockIdx.x;
  int b = bh >> 4, h = bh & 15;
  int t0 = blockIdx.y * 64;
  int t = threadIdx.x;
#pragma unroll
  for (int i = 0; i < 2; ++i) {
    int c = i * 256 + t;
    int tt = c >> 3, d8 = c & 7;
    bf16x8 v = *(const bf16x8*)(qkv + (size_t)(b * 2048 + t0 + tt) * 3072 + 2048 + h * 64 + d8 * 8);
    *(bf16x8*)&tile[(tt * 8 + (d8 ^ (tt >> 3))) * 8] = v;
  }
  __syncthreads();
#pragma unroll
  for (int i = 0; i < 2; ++i) {
    int c = i * 256 + t;
    int d = c >> 3, tt8 = c & 7;
    bf16x8 o;
#pragma unroll
    for (int j = 0; j < 8; ++j) {
      int row = tt8 * 8 + j;
      o[j] = tile[(row * 8 + ((d >> 3) ^ (row >> 3))) * 8 + (d & 7)];
    }
    *(bf16x8*)(vt + (size_t)(bh * 64 + d) * 2048 + t0 + tt8 * 8) = o;
  }
}

// Flash causal attention, fixed-cap softmax (no running max / no rescale).
// One wave = 16 q-rows of one head; KVBLK=64; K and V^T fragments read
// DIRECTLY from global (L1-resident tiles, no LDS staging, no barriers).
// P transposed through per-wave swizzled LDS (2KB). Big-q-first dispatch.
__global__ __launch_bounds__(256)
void attn_flash(const bf16* __restrict__ qkv, const bf16* __restrict__ vt,
                bf16* __restrict__ y)
{
  __shared__ alignas(16) bf16 lp[4][16 * 64];
  int t = threadIdx.x;
  int w = t >> 6, l = t & 63;
  int uid = blockIdx.x * 4 + w;              // 0..8191
  int qt = 127 - (uid >> 6);                 // big q-blocks dispatched first
  int bh = uid & 63;
  int b = bh >> 4, h = bh & 15;
  int t0 = qt * 16;
  int lr = l & 15, lg = l >> 4;
  const size_t RS = 3072;
  const float SCL = 0.18033688011112042f;    // 0.125 * log2(e)

  const bf16* qbase = qkv + (size_t)(b * 2048) * RS + h * 64;
  const bf16* kbase = qkv + (size_t)(b * 2048) * RS + 1024 + h * 64;
  const bf16* vtb   = vt + (size_t)(bh * 64) * 2048;

  bf16x8 qf[2];
#pragma unroll
  for (int kk = 0; kk < 2; ++kk)
    qf[kk] = *(const bf16x8*)(qbase + (size_t)(t0 + lr) * RS + kk * 32 + lg * 8);

  f32x4 zero = {0.f, 0.f, 0.f, 0.f};
  f32x4 o[4];
#pragma unroll
  for (int ni = 0; ni < 4; ++ni) o[ni] = zero;
  float lo[4] = {0.f, 0.f, 0.f, 0.f};

  int nkb = (t0 + 16 + 63) >> 6;
  for (int kb = 0; kb < nkb; ++kb) {
    int k0 = kb * 64;

    // QK^T: s[j] covers keys k0 + j*16 + lr (frags straight from global)
    f32x4 s[4];
#pragma unroll
    for (int j = 0; j < 4; ++j) s[j] = zero;
#pragma unroll
    for (int kk = 0; kk < 2; ++kk)
#pragma unroll
      for (int j = 0; j < 4; ++j) {
        bf16x8 kf = *(const bf16x8*)(kbase + (size_t)(k0 + j * 16 + lr) * RS + kk * 32 + lg * 8);
        s[j] = __builtin_amdgcn_mfma_f32_16x16x32_bf16(qf[kk], kf, s[j], 0, 0, 0);
      }

    // fixed-cap softmax: p = exp2(s*SCL), masked -> 0; lo = per-lane partial
    bool needmask = (k0 + 63 > t0);
    float p[4][4];
#pragma unroll
    for (int r = 0; r < 4; ++r) {
      int tq = t0 + lg * 4 + r;
#pragma unroll
      for (int j = 0; j < 4; ++j) {
        float v = s[j][r] * SCL;
        if (needmask && (k0 + j * 16 + lr > tq)) v = -1e30f;
        p[j][r] = exp2f(v);
      }
      lo[r] += (p[0][r] + p[1][r]) + (p[2][r] + p[3][r]);
    }

    // P -> per-wave swizzled LDS, read back as MFMA A-fragments
#pragma unroll
    for (int r = 0; r < 4; ++r) {
      int qr = lg * 4 + r;
#pragma unroll
      for (int j = 0; j < 4; ++j) {
        int ch = (2 * j + (lr >> 3)) ^ (qr & 7);
        lp[w][qr * 64 + ch * 8 + (lr & 7)] = (bf16)p[j][r];
      }
    }
    bf16x8 pa[2];
#pragma unroll
    for (int kf = 0; kf < 2; ++kf)
      pa[kf] = *(const bf16x8*)&lp[w][lr * 64 + (((4 * kf + lg) ^ (lr & 7)) * 8)];

    // PV: V^T frags straight from global
#pragma unroll
    for (int ni = 0; ni < 4; ++ni)
#pragma unroll
      for (int kf = 0; kf < 2; ++kf) {
        int d = ni * 16 + lr;
        bf16x8 vf = *(const bf16x8*)(vtb + (size_t)d * 2048 + k0 + kf * 32 + lg * 8);
        o[ni] = __builtin_amdgcn_mfma_f32_16x16x32_bf16(pa[kf], vf, o[ni], 0, 0, 0);
      }
  }

  // one reduction at the end: sum lo partials across the 16-lane row group
#pragma unroll
  for (int r = 0; r < 4; ++r) {
#pragma unroll
    for (int off = 1; off < 16; off <<= 1) lo[r] += __shfl_xor(lo[r], off);
    lo[r] = 1.f / lo[r];
  }
#pragma unroll
  for (int ni = 0; ni < 4; ++ni)
#pragma unroll
    for (int r = 0; r < 4; ++r) {
      int tq = t0 + lg * 4 + r;
      y[(size_t)(b * 2048 + tq) * 1024 + h * 64 + ni * 16 + lr] = (bf16)(o[ni][r] * lo[r]);
    }
}

extern "C" void kernel_launch(void* const* d_in, const int* in_sizes, int n_in,
                              void* d_out, int out_size, void* d_ws, size_t ws_size,
                              hipStream_t stream) {
  (void)in_sizes; (void)n_in; (void)out_size; (void)ws_size;
  const float* x      = (const float*)d_in[0];
  const float* ln1w   = (const float*)d_in[1];
  const float* ln1b   = (const float*)d_in[2];
  const float* ln2w   = (const float*)d_in[3];
  const float* ln2b   = (const float*)d_in[4];
  const float* w_attn = (const float*)d_in[5];
  const float* b_attn = (const float*)d_in[6];
  const float* w_proj = (const float*)d_in[7];
  const float* b_proj = (const float*)d_in[8];
  const float* w_fc   = (const float*)d_in[9];
  const float* b_fc   = (const float*)d_in[10];
  const float* w_fc2  = (const float*)d_in[11];
  const float* b_fc2  = (const float*)d_in[12];
  float* out = (float*)d_out;

  // workspace layout: h | [qkv | y] == m | x1 (vt overlays x1) | weightsT
  char* p = (char*)d_ws;
  bf16*  h     = (bf16*)p;  p += (size_t)8192 * 1024 * 2;
  bf16*  qkv   = (bf16*)p;
  bf16*  mbuf  = (bf16*)p;  p += (size_t)8192 * 3072 * 2;   // m overlays qkv+y
  bf16*  ybuf  = (bf16*)p;  p += (size_t)8192 * 1024 * 2;
  float* x1    = (float*)p; p += (size_t)8192 * 1024 * 4;
  bf16*  wqkvT = (bf16*)p;  p += (size_t)3072 * 1024 * 2;
  bf16*  wprojT= (bf16*)p;  p += (size_t)1024 * 1024 * 2;
  bf16*  wfcT  = (bf16*)p;  p += (size_t)4096 * 1024 * 2;
  bf16*  wfc2T = (bf16*)p;  p += (size_t)1024 * 4096 * 2;
  bf16*  vt    = (bf16*)x1;   // dead until proj-GEMM writes x1 (after attn)

  transpose_cast<<<dim3(1024 / 32, 3072 / 32), 256, 0, stream>>>(w_attn, wqkvT, 1024, 3072);
  transpose_cast<<<dim3(1024 / 32, 1024 / 32), 256, 0, stream>>>(w_proj, wprojT, 1024, 1024);
  transpose_cast<<<dim3(1024 / 32, 4096 / 32), 256, 0, stream>>>(w_fc,   wfcT,  1024, 4096);
  transpose_cast<<<dim3(4096 / 32, 1024 / 32), 256, 0, stream>>>(w_fc2,  wfc2T, 4096, 1024);

  ln_bf16<<<8192, 256, 0, stream>>>(x, ln1w, ln1b, h);
  gemm_bt<0><<<64 * 24, 256, 0, stream>>>(h, wqkvT, b_attn, nullptr, qkv, 8192, 3072, 1024);
  vtrans<<<dim3(64, 32), 256, 0, stream>>>(qkv, vt);
  attn_flash<<<2048, 256, 0, stream>>>(qkv, vt, ybuf);
  gemm_bt<1><<<64 * 8, 256, 0, stream>>>(ybuf, wprojT, b_proj, x, x1, 8192, 1024, 1024);
  ln_bf16<<<8192, 256, 0, stream>>>(x1, ln2w, ln2b, h);
  gemm_bt<2><<<64 * 32, 256, 0, stream>>>(h, wfcT, b_fc, nullptr, mbuf, 8192, 4096, 1024);
  gemm_bt<1><<<64 * 8, 256, 0, stream>>>(mbuf, wfc2T, b_fc2, x1, out, 8192, 1024, 4096);
}

// Round 4
// 455.967 us; speedup vs baseline: 1.2947x; 1.2947x over previous
//
#include <hip/hip_runtime.h>
#include <hip/hip_bf16.h>
#include <math.h>

typedef __bf16 bf16;
typedef __bf16 bf16x8 __attribute__((ext_vector_type(8)));
typedef float f32x4 __attribute__((ext_vector_type(4)));

#define BM 128
#define BN 128
#define BK 32

__device__ __forceinline__ void gload_lds16(const bf16* g, bf16* l) {
  __builtin_amdgcn_global_load_lds(
      (const __attribute__((address_space(1))) void*)g,
      (__attribute__((address_space(3))) void*)l, 16, 0, 0);
}

// C[M,N] = A[M,K] @ BT[N,K]^T, bf16 inputs, fp32 accum.
// EPI 0: out bf16 = acc + bias
// EPI 1: out f32  = acc + bias + res
// EPI 2: out bf16 = gelu_exact(acc + bias)
template <int EPI>
__global__ __launch_bounds__(256, 2)
void gemm_bt(const bf16* __restrict__ A, const bf16* __restrict__ BT,
             const float* __restrict__ bias, const float* __restrict__ res,
             void* __restrict__ Cout, int M, int N, int K)
{
  __shared__ alignas(16) bf16 lsA[BM * BK];
  __shared__ alignas(16) bf16 lsB[BN * BK];

  int nbn = N / BN;
  int nwg = (M / BM) * nbn;
  int bid = blockIdx.x;
  int cpx = nwg >> 3;                       // all grids divisible by 8
  int wg  = (bid & 7) * cpx + (bid >> 3);   // XCD-aware swizzle (bijective)
  int m0 = (wg / nbn) * BM;
  int n0 = (wg % nbn) * BN;

  int t  = threadIdx.x;
  int l  = t & 63;
  int w  = t >> 6;
  int wm = (w >> 1) * 64;
  int wn = (w & 1) * 64;
  int lr = l & 15;
  int lg = l >> 4;

  f32x4 acc[4][4];
  f32x4 zero = {0.f, 0.f, 0.f, 0.f};
#pragma unroll
  for (int mi = 0; mi < 4; ++mi)
#pragma unroll
    for (int ni = 0; ni < 4; ++ni) acc[mi][ni] = zero;

  for (int k0 = 0; k0 < K; k0 += BK) {
#pragma unroll
    for (int i = 0; i < 2; ++i) {
      int c = i * 256 + t;
      gload_lds16(A  + (size_t)(m0 + (c >> 2)) * K + k0 + ((c & 3) << 3), &lsA[c * 8]);
      gload_lds16(BT + (size_t)(n0 + (c >> 2)) * K + k0 + ((c & 3) << 3), &lsB[c * 8]);
    }
    __syncthreads();

    bf16x8 af[4], bfr[4];
#pragma unroll
    for (int mi = 0; mi < 4; ++mi)
      af[mi] = *(const bf16x8*)&lsA[(wm + mi * 16 + lr) * BK + lg * 8];
#pragma unroll
    for (int ni = 0; ni < 4; ++ni)
      bfr[ni] = *(const bf16x8*)&lsB[(wn + ni * 16 + lr) * BK + lg * 8];

#pragma unroll
    for (int mi = 0; mi < 4; ++mi)
#pragma unroll
      for (int ni = 0; ni < 4; ++ni)
        acc[mi][ni] = __builtin_amdgcn_mfma_f32_16x16x32_bf16(af[mi], bfr[ni], acc[mi][ni], 0, 0, 0);
    __syncthreads();
  }

#pragma unroll
  for (int mi = 0; mi < 4; ++mi) {
    int row = m0 + wm + mi * 16 + lg * 4;
#pragma unroll
    for (int ni = 0; ni < 4; ++ni) {
      int col = n0 + wn + ni * 16 + lr;
      float bv = bias[col];
      f32x4 a = acc[mi][ni];
#pragma unroll
      for (int r = 0; r < 4; ++r) {
        float v = a[r] + bv;
        size_t idx = (size_t)(row + r) * N + col;
        if (EPI == 0) {
          ((bf16*)Cout)[idx] = (bf16)v;
        } else if (EPI == 1) {
          ((float*)Cout)[idx] = v + res[idx];
        } else {
          v = 0.5f * v * (1.f + erff(v * 0.70710678118654752f));
          ((bf16*)Cout)[idx] = (bf16)v;
        }
      }
    }
  }
}

// LayerNorm over last dim (1024), fp32 in -> bf16 out. One block per row.
__global__ __launch_bounds__(256)
void ln_bf16(const float* __restrict__ x, const float* __restrict__ w,
             const float* __restrict__ b, bf16* __restrict__ out)
{
  int row = blockIdx.x;
  int t = threadIdx.x;
  float4 v = ((const float4*)(x + (size_t)row * 1024))[t];
  float s  = v.x + v.y + v.z + v.w;
  float sq = v.x * v.x + v.y * v.y + v.z * v.z + v.w * v.w;
#pragma unroll
  for (int off = 32; off >= 1; off >>= 1) {
    s  += __shfl_xor(s, off);
    sq += __shfl_xor(sq, off);
  }
  __shared__ float ps[4], pq[4];
  if ((t & 63) == 0) { ps[t >> 6] = s; pq[t >> 6] = sq; }
  __syncthreads();
  s  = ps[0] + ps[1] + ps[2] + ps[3];
  sq = pq[0] + pq[1] + pq[2] + pq[3];
  float mu  = s * (1.f / 1024.f);
  float var = sq * (1.f / 1024.f) - mu * mu;
  float rstd = rsqrtf(var + 1e-5f);
  float4 wv = ((const float4*)w)[t];
  float4 bv = ((const float4*)b)[t];
  size_t o0 = (size_t)row * 1024 + t * 4;
  out[o0 + 0] = (bf16)((v.x - mu) * rstd * wv.x + bv.x);
  out[o0 + 1] = (bf16)((v.y - mu) * rstd * wv.y + bv.y);
  out[o0 + 2] = (bf16)((v.z - mu) * rstd * wv.z + bv.z);
  out[o0 + 3] = (bf16)((v.w - mu) * rstd * wv.w + bv.w);
}

// WT[N,K] (bf16) = W[K,N] (f32) transposed+cast. grid=(K/32, N/32), 256 thr.
__global__ __launch_bounds__(256)
void transpose_cast(const float* __restrict__ W, bf16* __restrict__ WT, int K, int N)
{
  __shared__ float tile[32][33];
  int bk = blockIdx.x * 32, bn = blockIdx.y * 32;
  int tx = threadIdx.x & 31, ty = threadIdx.x >> 5;
#pragma unroll
  for (int i = ty; i < 32; i += 8)
    tile[i][tx] = W[(size_t)(bk + i) * N + bn + tx];
  __syncthreads();
#pragma unroll
  for (int i = ty; i < 32; i += 8)
    WT[(size_t)(bn + i) * K + bk + tx] = (bf16)tile[tx][i];
}

// V transpose: vt[(b*16+h)*64 + d][t] = qkv[(b*2048+t)*3072 + 2048 + h*64 + d]
// 64 tokens x 64 dims per block; XOR-swizzled LDS chunks. grid=(64, 32).
__global__ __launch_bounds__(256)
void vtrans(const bf16* __restrict__ qkv, bf16* __restrict__ vt)
{
  __shared__ alignas(16) bf16 tile[64 * 64];
  int bh = blockIdx.x;
  int b = bh >> 4, h = bh & 15;
  int t0 = blockIdx.y * 64;
  int t = threadIdx.x;
#pragma unroll
  for (int i = 0; i < 2; ++i) {
    int c = i * 256 + t;
    int tt = c >> 3, d8 = c & 7;
    bf16x8 v = *(const bf16x8*)(qkv + (size_t)(b * 2048 + t0 + tt) * 3072 + 2048 + h * 64 + d8 * 8);
    *(bf16x8*)&tile[(tt * 8 + (d8 ^ (tt >> 3))) * 8] = v;
  }
  __syncthreads();
#pragma unroll
  for (int i = 0; i < 2; ++i) {
    int c = i * 256 + t;
    int d = c >> 3, tt8 = c & 7;
    bf16x8 o;
#pragma unroll
    for (int j = 0; j < 8; ++j) {
      int row = tt8 * 8 + j;
      o[j] = tile[(row * 8 + ((d >> 3) ^ (row >> 3))) * 8 + (d & 7)];
    }
    *(bf16x8*)(vt + (size_t)(bh * 64 + d) * 2048 + t0 + tt8 * 8) = o;
  }
}

// Flash causal attention, block-cooperative (r2 structure) + fixed-cap
// softmax (r3's verified simplification): p = exp2(s*SCL), masked->0, no
// running max / no rescale — numerator & denominator scale cancels exactly.
// Block = 4 waves = 64 q-rows of one head; KVBLK=64; K/V^T staged to LDS
// (XOR-swizzled via pre-swizzled global_load_lds source). Big-q first.
__global__ __launch_bounds__(256)
void attn_flash(const bf16* __restrict__ qkv, const bf16* __restrict__ vt,
                bf16* __restrict__ y)
{
  __shared__ alignas(16) bf16 lk[64 * 64];
  __shared__ alignas(16) bf16 lv[64 * 64];
  __shared__ alignas(16) bf16 lp[4][16 * 64];

  int bid = blockIdx.x;
  int bh = bid & 63;
  int qb = 31 - (bid >> 6);
  int b = bh >> 4, h = bh & 15;
  int t = threadIdx.x;
  int w = t >> 6, l = t & 63;
  int lr = l & 15, lg = l >> 4;
  int q0 = qb * 64;
  int qw = q0 + w * 16;
  const size_t RS = 3072;
  const float SCL = 0.18033688011112042f;   // 0.125 * log2(e)

  const bf16* qbase = qkv + (size_t)(b * 2048) * RS + h * 64;
  const bf16* kbase = qkv + (size_t)(b * 2048) * RS + 1024 + h * 64;
  const bf16* vtb   = vt + (size_t)(bh * 64) * 2048;

  bf16x8 qf[2];
#pragma unroll
  for (int kk = 0; kk < 2; ++kk)
    qf[kk] = *(const bf16x8*)(qbase + (size_t)(qw + lr) * RS + kk * 32 + lg * 8);

  f32x4 zero = {0.f, 0.f, 0.f, 0.f};
  f32x4 o[4];
#pragma unroll
  for (int ni = 0; ni < 4; ++ni) o[ni] = zero;
  float lo[4] = {0.f, 0.f, 0.f, 0.f};

  int nkb = qb + 1;
  for (int kb = 0; kb < nkb; ++kb) {
    int k0 = kb * 64;
    // stage K tile [64 keys][64 d] and V^T tile [64 d][64 keys], swizzled src
#pragma unroll
    for (int i = 0; i < 2; ++i) {
      int c = i * 256 + t;
      int row = c >> 3, c8 = c & 7;
      int sc8 = c8 ^ (row & 7);
      gload_lds16(kbase + (size_t)(k0 + row) * RS + sc8 * 8, &lk[c * 8]);
      gload_lds16(vtb + (size_t)row * 2048 + k0 + sc8 * 8, &lv[c * 8]);
    }
    __syncthreads();

    // QK^T: s[j] covers keys k0 + j*16 + lr
    f32x4 s[4];
#pragma unroll
    for (int j = 0; j < 4; ++j) s[j] = zero;
#pragma unroll
    for (int kk = 0; kk < 2; ++kk)
#pragma unroll
      for (int j = 0; j < 4; ++j) {
        int krow = j * 16 + lr;
        bf16x8 kf = *(const bf16x8*)&lk[krow * 64 + (((4 * kk + lg) ^ (krow & 7)) * 8)];
        s[j] = __builtin_amdgcn_mfma_f32_16x16x32_bf16(qf[kk], kf, s[j], 0, 0, 0);
      }

    // fixed-cap softmax: p = exp2(s*SCL); masked -> 0; lo = per-lane partial
    bool needmask = (kb == qb);
    float p[4][4];
#pragma unroll
    for (int r = 0; r < 4; ++r) {
      int tq = qw + lg * 4 + r;
#pragma unroll
      for (int j = 0; j < 4; ++j) {
        float v = s[j][r] * SCL;
        if (needmask && (k0 + j * 16 + lr > tq)) v = -1e30f;
        p[j][r] = exp2f(v);
      }
      lo[r] += (p[0][r] + p[1][r]) + (p[2][r] + p[3][r]);
    }

    // P -> per-wave swizzled LDS, read back as MFMA A-fragments
#pragma unroll
    for (int r = 0; r < 4; ++r) {
      int qr = lg * 4 + r;
#pragma unroll
      for (int j = 0; j < 4; ++j) {
        int ch = (2 * j + (lr >> 3)) ^ (qr & 7);
        lp[w][qr * 64 + ch * 8 + (lr & 7)] = (bf16)p[j][r];
      }
    }
    bf16x8 pa[2];
#pragma unroll
    for (int kf = 0; kf < 2; ++kf)
      pa[kf] = *(const bf16x8*)&lp[w][lr * 64 + (((4 * kf + lg) ^ (lr & 7)) * 8)];

    // PV from staged V^T
#pragma unroll
    for (int ni = 0; ni < 4; ++ni)
#pragma unroll
      for (int kf = 0; kf < 2; ++kf) {
        int d = ni * 16 + lr;
        bf16x8 vf = *(const bf16x8*)&lv[d * 64 + (((4 * kf + lg) ^ (d & 7)) * 8)];
        o[ni] = __builtin_amdgcn_mfma_f32_16x16x32_bf16(pa[kf], vf, o[ni], 0, 0, 0);
      }
    __syncthreads();
  }

  // one reduction at the end: sum lo partials across the 16-lane row group
#pragma unroll
  for (int r = 0; r < 4; ++r) {
#pragma unroll
    for (int off = 1; off < 16; off <<= 1) lo[r] += __shfl_xor(lo[r], off);
    lo[r] = 1.f / lo[r];
  }
#pragma unroll
  for (int ni = 0; ni < 4; ++ni)
#pragma unroll
    for (int r = 0; r < 4; ++r) {
      int tq = qw + lg * 4 + r;
      y[(size_t)(b * 2048 + tq) * 1024 + h * 64 + ni * 16 + lr] = (bf16)(o[ni][r] * lo[r]);
    }
}

extern "C" void kernel_launch(void* const* d_in, const int* in_sizes, int n_in,
                              void* d_out, int out_size, void* d_ws, size_t ws_size,
                              hipStream_t stream) {
  (void)in_sizes; (void)n_in; (void)out_size; (void)ws_size;
  const float* x      = (const float*)d_in[0];
  const float* ln1w   = (const float*)d_in[1];
  const float* ln1b   = (const float*)d_in[2];
  const float* ln2w   = (const float*)d_in[3];
  const float* ln2b   = (const float*)d_in[4];
  const float* w_attn = (const float*)d_in[5];
  const float* b_attn = (const float*)d_in[6];
  const float* w_proj = (const float*)d_in[7];
  const float* b_proj = (const float*)d_in[8];
  const float* w_fc   = (const float*)d_in[9];
  const float* b_fc   = (const float*)d_in[10];
  const float* w_fc2  = (const float*)d_in[11];
  const float* b_fc2  = (const float*)d_in[12];
  float* out = (float*)d_out;

  // workspace layout: h | [qkv | y] == m | x1 (vt overlays x1) | weightsT
  char* p = (char*)d_ws;
  bf16*  h     = (bf16*)p;  p += (size_t)8192 * 1024 * 2;
  bf16*  qkv   = (bf16*)p;
  bf16*  mbuf  = (bf16*)p;  p += (size_t)8192 * 3072 * 2;   // m overlays qkv+y
  bf16*  ybuf  = (bf16*)p;  p += (size_t)8192 * 1024 * 2;
  float* x1    = (float*)p; p += (size_t)8192 * 1024 * 4;
  bf16*  wqkvT = (bf16*)p;  p += (size_t)3072 * 1024 * 2;
  bf16*  wprojT= (bf16*)p;  p += (size_t)1024 * 1024 * 2;
  bf16*  wfcT  = (bf16*)p;  p += (size_t)4096 * 1024 * 2;
  bf16*  wfc2T = (bf16*)p;  p += (size_t)1024 * 4096 * 2;
  bf16*  vt    = (bf16*)x1;   // dead until proj-GEMM writes x1 (after attn)

  transpose_cast<<<dim3(1024 / 32, 3072 / 32), 256, 0, stream>>>(w_attn, wqkvT, 1024, 3072);
  transpose_cast<<<dim3(1024 / 32, 1024 / 32), 256, 0, stream>>>(w_proj, wprojT, 1024, 1024);
  transpose_cast<<<dim3(1024 / 32, 4096 / 32), 256, 0, stream>>>(w_fc,   wfcT,  1024, 4096);
  transpose_cast<<<dim3(4096 / 32, 1024 / 32), 256, 0, stream>>>(w_fc2,  wfc2T, 4096, 1024);

  ln_bf16<<<8192, 256, 0, stream>>>(x, ln1w, ln1b, h);
  gemm_bt<0><<<64 * 24, 256, 0, stream>>>(h, wqkvT, b_attn, nullptr, qkv, 8192, 3072, 1024);
  vtrans<<<dim3(64, 32), 256, 0, stream>>>(qkv, vt);
  attn_flash<<<2048, 256, 0, stream>>>(qkv, vt, ybuf);
  gemm_bt<1><<<64 * 8, 256, 0, stream>>>(ybuf, wprojT, b_proj, x, x1, 8192, 1024, 1024);
  ln_bf16<<<8192, 256, 0, stream>>>(x1, ln2w, ln2b, h);
  gemm_bt<2><<<64 * 32, 256, 0, stream>>>(h, wfcT, b_fc, nullptr, mbuf, 8192, 4096, 1024);
  gemm_bt<1><<<64 * 8, 256, 0, stream>>>(mbuf, wfc2T, b_fc2, x1, out, 8192, 1024, 4096);
}